// Round 5
// baseline (448.109 us; speedup 1.0000x reference)
//
#include <hip/hip_runtime.h>
#include <hip/hip_bf16.h>
#include <stdint.h>

typedef unsigned short u16;
typedef unsigned int u32;
typedef __attribute__((ext_vector_type(8))) short bf16x8;   // 8 bf16 in 4 VGPRs
typedef __attribute__((ext_vector_type(4))) float f32x4;

#define S_LEN 2048
#define D_DIM 1024
#define H_DIM 1024
#define BATCH 8
#define M_TOTAL (BATCH * S_LEN)   // 16384

__device__ __forceinline__ u16 f2b(float f) {
  u32 u = __builtin_bit_cast(u32, f);
  u32 r = (u + 0x7fffu + ((u >> 16) & 1u)) >> 16;   // RNE
  return (u16)r;
}

// ---- merged prep kernel ----
// blocks [0, 8192): cast x fp32->bf16, 8 elems/thread
// blocks [8192, 8192+3072): transpose-cast Wq/Wk/Wv (z = idx/1024), 32x32 tiles
// side jobs: bias concat into bqk, zero lsum.
__global__ __launch_bounds__(256) void prep_kernel(
    const float* __restrict__ x, const float* __restrict__ Wq,
    const float* __restrict__ Wk, const float* __restrict__ Wv,
    const float* __restrict__ bq, const float* __restrict__ bk,
    u16* __restrict__ xb, u16* __restrict__ Wtqk, u16* __restrict__ Wtv,
    float* __restrict__ bqk, float* __restrict__ lsum) {
  int blk = blockIdx.x;
  if (blk < 8192) {
    int i = blk * 256 + threadIdx.x;           // i < 2,097,152
    const float4* p = (const float4*)x;
    float4 a = p[2 * i], b = p[2 * i + 1];
    u32 w0 = (u32)f2b(a.x) | ((u32)f2b(a.y) << 16);
    u32 w1 = (u32)f2b(a.z) | ((u32)f2b(a.w) << 16);
    u32 w2 = (u32)f2b(b.x) | ((u32)f2b(b.y) << 16);
    u32 w3 = (u32)f2b(b.z) | ((u32)f2b(b.w) << 16);
    ((uint4*)xb)[i] = make_uint4(w0, w1, w2, w3);
    return;
  }
  __shared__ float tile[32][33];
  int idx = blk - 8192;                        // 0..3071
  int z = idx >> 10;                           // 0..2
  int t = idx & 1023;                          // 32x32 tile id
  const float* W = (z == 0) ? Wq : (z == 1) ? Wk : Wv;
  u16* Wt = (z == 0) ? Wtqk : (z == 1) ? (Wtqk + 1024 * 1024) : Wtv;
  int h0 = (t & 31) * 32, d0 = (t >> 5) * 32;
  int tx = threadIdx.x & 31, ty = threadIdx.x >> 5;
#pragma unroll
  for (int r = ty; r < 32; r += 8)
    tile[r][tx] = W[(size_t)(d0 + r) * H_DIM + h0 + tx];
  if (t == 0) {
    if (z == 0) {
      for (int i = threadIdx.x; i < 1024; i += 256) bqk[i] = bq[i];
    } else if (z == 1) {
      for (int i = threadIdx.x; i < 1024; i += 256) bqk[1024 + i] = bk[i];
    } else {
      for (int i = threadIdx.x; i < M_TOTAL; i += 256) lsum[i] = 0.f;
    }
  }
  __syncthreads();
#pragma unroll
  for (int r = ty; r < 32; r += 8)
    Wt[(size_t)(h0 + r) * D_DIM + d0 + tx] = f2b(tile[tx][r]);
}

// ---------------- GEMM: C[M][N] = A[M][K] * Bt[N][K]^T ----------------
// 128x128 block tile, 4 waves (2x2 of 64x64), BK=64, mfma_f32_16x16x32_bf16.
// This exact fragment-read geometry measured ZERO SQ_LDS_BANK_CONFLICT; the
// 32x32-MFMA geometry measured 4 extra cyc/ds_read_b128 (round 3) — keep 16x16.
// Staging: global_load_lds width=16, XOR chunk swizzle applied on the GLOBAL
// source index (LDS dest must stay wave-uniform-base + lane*16).
// All dims/strides are compile-time: shift addressing + known trip counts.
// BIAS: 0 none, 1 bias[col], 2 bias[row].
// EPI:  0 plain, 1 exp2(acc*scale)->bf16 + row-sum atomics into lsum,
//       2 acc * 1/lsum[row] (softmax normalize).
template <int BIAS, int EPI, bool OUT_BF16, int KDIM, int LDA, int LDB, int LDC,
          long long ABATCH, long long BBATCH, long long CBATCH, int MROWS>
__global__ __launch_bounds__(256) void gemm16(
    const u16* __restrict__ A, const u16* __restrict__ Bt, void* __restrict__ Cout,
    const float* __restrict__ bias, float* __restrict__ lsum, float scale) {
  __shared__ __align__(16) u16 As[128 * 64];
  __shared__ __align__(16) u16 Bs[128 * 64];
  const int tid = threadIdx.x;
  const int wave = tid >> 6, lane = tid & 63;
  const int quad = lane >> 4, lr = lane & 15;
  const int wr = (wave >> 1) * 64, wc = (wave & 1) * 64;
  const int row0 = blockIdx.x * 128, col0 = blockIdx.y * 128;
  A += (size_t)blockIdx.z * (size_t)ABATCH;
  Bt += (size_t)blockIdx.z * (size_t)BBATCH;

  f32x4 acc[4][4] = {};

  auto AsL = (__attribute__((address_space(3))) char*)As;
  auto BsL = (__attribute__((address_space(3))) char*)Bs;
  const char* Ab = (const char*)A;
  const char* Bb = (const char*)Bt;

  for (int k0 = 0; k0 < KDIM; k0 += 64) {
    // ---- stage A/B tiles: 128 rows x 64 bf16 = 16 KB each, 4 rounds x 256 x 16B
#pragma unroll
    for (int rr = 0; rr < 4; ++rr) {
      int chunk = rr * 256 + tid;          // row*8 + store-chunk
      int row = chunk >> 3;
      int cs = (chunk & 7) ^ (row & 7);    // swizzled source chunk in the row
      const void* ga = Ab + (((size_t)(row0 + row) * LDA + (size_t)k0 + cs * 8) * 2);
      __builtin_amdgcn_global_load_lds(
          (const __attribute__((address_space(1))) void*)ga,
          (__attribute__((address_space(3))) void*)(AsL + chunk * 16), 16, 0, 0);
      const void* gb = Bb + (((size_t)(col0 + row) * LDB + (size_t)k0 + cs * 8) * 2);
      __builtin_amdgcn_global_load_lds(
          (const __attribute__((address_space(1))) void*)gb,
          (__attribute__((address_space(3))) void*)(BsL + chunk * 16), 16, 0, 0);
    }
    __syncthreads();
    // ---- compute: 2 k-steps of 32, 16 MFMAs each
#pragma unroll
    for (int ks = 0; ks < 2; ++ks) {
      bf16x8 af[4], bf[4];
#pragma unroll
      for (int i = 0; i < 4; ++i) {
        int r = wr + i * 16 + lr;
        int cc = (ks * 4 + quad) ^ (r & 7);
        af[i] = *(const bf16x8*)&As[r * 64 + cc * 8];
      }
#pragma unroll
      for (int j = 0; j < 4; ++j) {
        int r = wc + j * 16 + lr;
        int cc = (ks * 4 + quad) ^ (r & 7);
        bf[j] = *(const bf16x8*)&Bs[r * 64 + cc * 8];
      }
#pragma unroll
      for (int i = 0; i < 4; ++i)
#pragma unroll
        for (int j = 0; j < 4; ++j)
          acc[i][j] = __builtin_amdgcn_mfma_f32_16x16x32_bf16(af[i], bf[j],
                                                              acc[i][j], 0, 0, 0);
    }
    __syncthreads();
  }

  // ---- epilogue. 16x16 C/D layout: col=lane&15, row=quad*4+reg (m89/m91-verified)
  const long long lrow0 = (long long)blockIdx.z * MROWS + row0;  // lsum row base

  if constexpr (EPI == 1) {
    // exp2 -> bf16 store + row-sum atomics into lsum (scale carries log2e)
    u16* C = (u16*)Cout + (size_t)blockIdx.z * (size_t)CBATCH;
#pragma unroll
    for (int i = 0; i < 4; ++i) {
#pragma unroll
      for (int ii = 0; ii < 4; ++ii) {
        int r = wr + i * 16 + quad * 4 + ii;
        float rowsum = 0.f;
#pragma unroll
        for (int j = 0; j < 4; ++j) {
          float e = exp2f(acc[i][j][ii] * scale);
          rowsum += e;
          C[(size_t)(row0 + r) * LDC + (col0 + wc + j * 16 + lr)] = f2b(e);
        }
        // reduce over the 16 lanes of the quad (xor masks stay in-group)
#pragma unroll
        for (int off = 1; off < 16; off <<= 1) rowsum += __shfl_xor(rowsum, off);
        if (lr == 0) atomicAdd(lsum + lrow0 + r, rowsum);
      }
    }
    return;
  }

#pragma unroll
  for (int i = 0; i < 4; ++i) {
#pragma unroll
    for (int ii = 0; ii < 4; ++ii) {
      int r = wr + i * 16 + quad * 4 + ii;
      float radd = 0.f, rmul = 1.f;
      if (BIAS == 2) radd = bias[row0 + r];
      if (EPI == 2) rmul = 1.0f / lsum[lrow0 + r];
#pragma unroll
      for (int j = 0; j < 4; ++j) {
        int c = col0 + wc + j * 16 + lr;
        float v = acc[i][j][ii] * rmul + radd;
        if (BIAS == 1) v += bias[c];
        if constexpr (OUT_BF16) {
          u16* C = (u16*)Cout + (size_t)blockIdx.z * (size_t)CBATCH;
          C[(size_t)(row0 + r) * LDC + c] = f2b(v);
        } else {
          float* C = (float*)Cout + (size_t)blockIdx.z * (size_t)CBATCH;
          C[(size_t)(row0 + r) * LDC + c] = v;
        }
      }
    }
  }
}

extern "C" void kernel_launch(void* const* d_in, const int* in_sizes, int n_in,
                              void* d_out, int out_size, void* d_ws, size_t ws_size,
                              hipStream_t stream) {
  const float* x = (const float*)d_in[0];
  const float* Wq = (const float*)d_in[1];
  const float* bq = (const float*)d_in[2];
  const float* Wk = (const float*)d_in[3];
  const float* bk = (const float*)d_in[4];
  const float* Wv = (const float*)d_in[5];
  const float* bv = (const float*)d_in[6];
  float* out = (float*)d_out;

  // workspace layout (bytes): total ~207 MB
  char* ws = (char*)d_ws;
  u16* xb = (u16*)ws;   ws += (size_t)M_TOTAL * D_DIM * 2;           // 33.5 MB
  u16* Wtqk = (u16*)ws; ws += (size_t)2 * H_DIM * D_DIM * 2;         // 4 MB
  u16* Wtv = (u16*)ws;  ws += (size_t)H_DIM * D_DIM * 2;             // 2 MB
  u16* QKm = (u16*)ws;  ws += (size_t)M_TOTAL * 2 * H_DIM * 2;       // 67 MB  [m][2048]
  u16* Vt = (u16*)ws;   ws += (size_t)BATCH * H_DIM * S_LEN * 2;     // 33.5 MB [b][h][s]
  u16* Sm = (u16*)ws;   ws += (size_t)BATCH * S_LEN * S_LEN * 2;     // 67 MB  [b][q][k]
  float* bqk = (float*)ws;  ws += 2048 * 4;
  float* lsum = (float*)ws; ws += (size_t)M_TOTAL * 4;               // 64 KB

  // 1) merged prep: x cast + 3 weight transpose-casts + bias concat + lsum zero
  prep_kernel<<<8192 + 3072, 256, 0, stream>>>(
      x, Wq, Wk, Wv, bq, bk, xb, Wtqk, Wtv, bqk, lsum);

  // 2) [Q|K] = xb * Wtqk^T + bqk  (M=16384, N=2048, K=1024)
  gemm16<1, 0, true, 1024, 1024, 1024, 2048, 0LL, 0LL, 0LL, M_TOTAL>
      <<<dim3(128, 16, 1), 256, 0, stream>>>(xb, Wtqk, QKm, bqk, nullptr, 0.f);

  // 3) Vt[b][h][s] = Wtv * xb_b^T + bv[row]  (M=1024, N=2048, K=1024, batched)
  gemm16<2, 0, true, 1024, 1024, 1024, 2048,
         0LL, (long long)S_LEN * D_DIM, (long long)H_DIM * S_LEN, H_DIM>
      <<<dim3(8, 16, BATCH), 256, 0, stream>>>(Wtv, xb, Vt, bv, nullptr, 0.f);

  // 4) P_hat[b][q][k] = exp(Q_b K_b^T / 32) -> bf16, row sums -> lsum (batched)
  //    scale = (1/32) * log2(e), applied with exp2f
  gemm16<0, 1, true, 1024, 2048, 2048, 2048,
         (long long)S_LEN * 2 * H_DIM, (long long)S_LEN * 2 * H_DIM,
         (long long)S_LEN * S_LEN, S_LEN>
      <<<dim3(16, 16, BATCH), 256, 0, stream>>>(QKm, QKm + H_DIM, Sm, nullptr,
                                                lsum, 0.045084190f);

  // 5) out[b][q][h] = (P_hat_b / lsum) * Vt_b^T  (M=2048, N=1024, K=2048)
  gemm16<0, 2, false, 2048, 2048, 2048, 1024,
         (long long)S_LEN * S_LEN, (long long)H_DIM * S_LEN,
         (long long)S_LEN * H_DIM, S_LEN>
      <<<dim3(16, 8, BATCH), 256, 0, stream>>>(Sm, Vt, out, nullptr, lsum, 0.f);
}

// Round 6
// 431.710 us; speedup vs baseline: 1.0380x; 1.0380x over previous
//
#include <hip/hip_runtime.h>
#include <hip/hip_bf16.h>
#include <stdint.h>

typedef unsigned short u16;
typedef unsigned int u32;
typedef __attribute__((ext_vector_type(8))) short bf16x8;   // 8 bf16 in 4 VGPRs
typedef __attribute__((ext_vector_type(4))) float f32x4;

#define S_LEN 2048
#define D_DIM 1024
#define H_DIM 1024
#define BATCH 8
#define M_TOTAL (BATCH * S_LEN)   // 16384

__device__ __forceinline__ u16 f2b(float f) {
  u32 u = __builtin_bit_cast(u32, f);
  u32 r = (u + 0x7fffu + ((u >> 16) & 1u)) >> 16;   // RNE
  return (u16)r;
}
__device__ __forceinline__ float b2f_lo(u32 w) {
  u32 u = w << 16;
  return __builtin_bit_cast(float, u);
}
__device__ __forceinline__ float b2f_hi(u32 w) {
  u32 u = w & 0xffff0000u;
  return __builtin_bit_cast(float, u);
}

// ---- merged prep kernel ----
// blocks [0,8192):        cast x fp32->bf16 (8 elems/thread)
// blocks [8192,8704):     cast Wq -> Wqb (plain, no transpose); blk 8192 zeroes lsum
// blocks [8704,9216):     cast Wk -> Wkb
// blocks [9216,10240):    transpose-cast Wv -> Wtv (32x32 tiles)
// blocks [10240,10496):   bvec[d] = sum_h Wk[d][h]*bq[h]  (wave per row, fp32)
__global__ __launch_bounds__(256) void prep_kernel(
    const float* __restrict__ x, const float* __restrict__ Wq,
    const float* __restrict__ Wk, const float* __restrict__ Wv,
    const float* __restrict__ bq,
    u16* __restrict__ xb, u16* __restrict__ Wqb, u16* __restrict__ Wkb,
    u16* __restrict__ Wtv, float* __restrict__ bvec, float* __restrict__ lsum) {
  int blk = blockIdx.x;
  if (blk < 9216) {
    const float* src;
    u16* dst;
    int i;
    if (blk < 8192) {
      src = x; dst = xb; i = blk * 256 + threadIdx.x;
    } else if (blk < 8704) {
      src = Wq; dst = Wqb; i = (blk - 8192) * 256 + threadIdx.x;
      if (blk == 8192) {
        for (int t = threadIdx.x; t < M_TOTAL; t += 256) lsum[t] = 0.f;
      }
    } else {
      src = Wk; dst = Wkb; i = (blk - 8704) * 256 + threadIdx.x;
    }
    const float4* p = (const float4*)src;
    float4 a = p[2 * i], b = p[2 * i + 1];
    u32 w0 = (u32)f2b(a.x) | ((u32)f2b(a.y) << 16);
    u32 w1 = (u32)f2b(a.z) | ((u32)f2b(a.w) << 16);
    u32 w2 = (u32)f2b(b.x) | ((u32)f2b(b.y) << 16);
    u32 w3 = (u32)f2b(b.z) | ((u32)f2b(b.w) << 16);
    ((uint4*)dst)[i] = make_uint4(w0, w1, w2, w3);
    return;
  }
  if (blk < 10240) {
    __shared__ float tile[32][33];
    int t = blk - 9216;                        // 32x32 tile id
    int h0 = (t & 31) * 32, d0 = (t >> 5) * 32;
    int tx = threadIdx.x & 31, ty = threadIdx.x >> 5;
#pragma unroll
    for (int r = ty; r < 32; r += 8)
      tile[r][tx] = Wv[(size_t)(d0 + r) * H_DIM + h0 + tx];
    __syncthreads();
#pragma unroll
    for (int r = ty; r < 32; r += 8)
      Wtv[(size_t)(h0 + r) * D_DIM + d0 + tx] = f2b(tile[tx][r]);
    return;
  }
  // bvec: wave per row of Wk
  int wave = threadIdx.x >> 6, lane = threadIdx.x & 63;
  int row = (blk - 10240) * 4 + wave;          // 0..1023
  const float4* wr = (const float4*)(Wk + (size_t)row * H_DIM);
  const float4* br = (const float4*)bq;
  float s = 0.f;
#pragma unroll
  for (int u = 0; u < 4; ++u) {
    float4 a = wr[lane * 4 + u];
    float4 b = br[lane * 4 + u];
    s += a.x * b.x + a.y * b.y + a.z * b.z + a.w * b.w;
  }
#pragma unroll
  for (int off = 1; off < 64; off <<= 1) s += __shfl_xor(s, off);
  if (lane == 0) bvec[row] = s;
}

// ---- v matvec: vb[m] = (xb[m,:] . bvec) * (1/32); wave per row ----
__global__ __launch_bounds__(256) void vvec_kernel(const u16* __restrict__ xb,
                                                   const float* __restrict__ bvec,
                                                   float* __restrict__ vb) {
  int wave = threadIdx.x >> 6, lane = threadIdx.x & 63;
  int row = blockIdx.x * 4 + wave;             // 0..16383
  const uint4* xr = (const uint4*)(xb + (size_t)row * D_DIM);
  const float4* br = (const float4*)bvec;
  float s = 0.f;
#pragma unroll
  for (int u = 0; u < 2; ++u) {                // 2 x uint4 = 16 bf16
    uint4 q = xr[lane * 2 + u];
    u32 w[4] = {q.x, q.y, q.z, q.w};
#pragma unroll
    for (int k = 0; k < 4; ++k) {
      float4 b = br[lane * 4 + u * 2 + (k >> 1)];
      float b0 = (k & 1) ? b.z : b.x;
      float b1 = (k & 1) ? b.w : b.y;
      s += b2f_lo(w[k]) * b0 + b2f_hi(w[k]) * b1;
    }
  }
#pragma unroll
  for (int off = 1; off < 64; off <<= 1) s += __shfl_xor(s, off);
  if (lane == 0) vb[row] = s * 0.03125f;
}

// ---------------- GEMM: C[M][N] = A[M][K] * Bt[N][K]^T ---------------- 
// Round-4 measured-good version (runtime dims — compile-time dims regressed R5).
// 128x128 tile, 4 waves (2x2 of 64x64), BK=64, mfma_f32_16x16x32_bf16; this
// fragment geometry measured ZERO SQ_LDS_BANK_CONFLICT. global_load_lds w=16,
// XOR chunk swizzle on the GLOBAL source index.
// BIAS: 0 none, 1 bias[col], 2 bias[row].
// EPI:  0 plain, 1 exp(acc*scale + vb[batch-col])->bf16 + row-sum atomics,
//       2 acc * 1/lsum[row].
template <int BIAS, int EPI, bool OUT_BF16>
__global__ __launch_bounds__(256) void gemm16(
    const u16* __restrict__ A, const u16* __restrict__ Bt, void* __restrict__ Cout,
    const float* __restrict__ bias, float* __restrict__ lsum,
    int M, int N, int K, int lda, int ldb, int ldc,
    long long aBatch, long long bBatch, long long cBatch, float scale) {
  __shared__ __align__(16) u16 As[128 * 64];
  __shared__ __align__(16) u16 Bs[128 * 64];
  const int tid = threadIdx.x;
  const int wave = tid >> 6, lane = tid & 63;
  const int quad = lane >> 4, lr = lane & 15;
  const int wr = (wave >> 1) * 64, wc = (wave & 1) * 64;
  const int row0 = blockIdx.x * 128, col0 = blockIdx.y * 128;
  A += (size_t)blockIdx.z * (size_t)aBatch;
  Bt += (size_t)blockIdx.z * (size_t)bBatch;

  f32x4 acc[4][4] = {};

  auto AsL = (__attribute__((address_space(3))) char*)As;
  auto BsL = (__attribute__((address_space(3))) char*)Bs;
  const char* Ab = (const char*)A;
  const char* Bb = (const char*)Bt;

  for (int k0 = 0; k0 < K; k0 += 64) {
#pragma unroll
    for (int rr = 0; rr < 4; ++rr) {
      int chunk = rr * 256 + tid;          // row*8 + store-chunk
      int row = chunk >> 3;
      int cs = (chunk & 7) ^ (row & 7);    // swizzled source chunk in the row
      const void* ga = Ab + (((size_t)(row0 + row) * lda + (size_t)k0 + cs * 8) * 2);
      __builtin_amdgcn_global_load_lds(
          (const __attribute__((address_space(1))) void*)ga,
          (__attribute__((address_space(3))) void*)(AsL + chunk * 16), 16, 0, 0);
      const void* gb = Bb + (((size_t)(col0 + row) * ldb + (size_t)k0 + cs * 8) * 2);
      __builtin_amdgcn_global_load_lds(
          (const __attribute__((address_space(1))) void*)gb,
          (__attribute__((address_space(3))) void*)(BsL + chunk * 16), 16, 0, 0);
    }
    __syncthreads();
#pragma unroll
    for (int ks = 0; ks < 2; ++ks) {
      bf16x8 af[4], bf[4];
#pragma unroll
      for (int i = 0; i < 4; ++i) {
        int r = wr + i * 16 + lr;
        int cc = (ks * 4 + quad) ^ (r & 7);
        af[i] = *(const bf16x8*)&As[r * 64 + cc * 8];
      }
#pragma unroll
      for (int j = 0; j < 4; ++j) {
        int r = wc + j * 16 + lr;
        int cc = (ks * 4 + quad) ^ (r & 7);
        bf[j] = *(const bf16x8*)&Bs[r * 64 + cc * 8];
      }
#pragma unroll
      for (int i = 0; i < 4; ++i)
#pragma unroll
        for (int j = 0; j < 4; ++j)
          acc[i][j] = __builtin_amdgcn_mfma_f32_16x16x32_bf16(af[i], bf[j],
                                                              acc[i][j], 0, 0, 0);
    }
    __syncthreads();
  }

  // ---- epilogue. 16x16 C/D layout: col=lane&15, row=quad*4+reg
  const long long lrow0 = (long long)blockIdx.z * M + row0;  // lsum row base

  if constexpr (EPI == 1) {
    // exp(acc*scale + vb[col]) -> bf16 store + row-sum atomics into lsum
    u16* C = (u16*)Cout + (size_t)blockIdx.z * (size_t)cBatch;
    float bb[4];
#pragma unroll
    for (int j = 0; j < 4; ++j)
      bb[j] = bias[(long long)blockIdx.z * N + col0 + wc + j * 16 + lr];
#pragma unroll
    for (int i = 0; i < 4; ++i) {
#pragma unroll
      for (int ii = 0; ii < 4; ++ii) {
        int r = wr + i * 16 + quad * 4 + ii;
        float rowsum = 0.f;
#pragma unroll
        for (int j = 0; j < 4; ++j) {
          float e = __expf(acc[i][j][ii] * scale + bb[j]);
          rowsum += e;
          C[(size_t)(row0 + r) * ldc + (col0 + wc + j * 16 + lr)] = f2b(e);
        }
#pragma unroll
        for (int off = 1; off < 16; off <<= 1) rowsum += __shfl_xor(rowsum, off);
        if (lr == 0) atomicAdd(lsum + lrow0 + r, rowsum);
      }
    }
    return;
  }

#pragma unroll
  for (int i = 0; i < 4; ++i) {
#pragma unroll
    for (int ii = 0; ii < 4; ++ii) {
      int r = wr + i * 16 + quad * 4 + ii;
      float radd = 0.f, rmul = 1.f;
      if (BIAS == 2) radd = bias[row0 + r];
      if (EPI == 2) rmul = 1.0f / lsum[lrow0 + r];
#pragma unroll
      for (int j = 0; j < 4; ++j) {
        int c = col0 + wc + j * 16 + lr;
        float v = acc[i][j][ii] * rmul + radd;
        if (BIAS == 1) v += bias[c];
        if constexpr (OUT_BF16) {
          u16* C = (u16*)Cout + (size_t)blockIdx.z * (size_t)cBatch;
          C[(size_t)(row0 + r) * ldc + c] = f2b(v);
        } else {
          float* C = (float*)Cout + (size_t)blockIdx.z * (size_t)cBatch;
          C[(size_t)(row0 + r) * ldc + c] = v;
        }
      }
    }
  }
}

extern "C" void kernel_launch(void* const* d_in, const int* in_sizes, int n_in,
                              void* d_out, int out_size, void* d_ws, size_t ws_size,
                              hipStream_t stream) {
  const float* x = (const float*)d_in[0];
  const float* Wq = (const float*)d_in[1];
  const float* bq = (const float*)d_in[2];
  const float* Wk = (const float*)d_in[3];
  // bk unused: its softmax contribution is row-constant and cancels exactly
  const float* Wv = (const float*)d_in[5];
  const float* bv = (const float*)d_in[6];
  float* out = (float*)d_out;

  // workspace layout (bytes): total ~176 MB
  char* ws = (char*)d_ws;
  u16* xb = (u16*)ws;   ws += (size_t)M_TOTAL * D_DIM * 2;           // 33.5 MB
  u16* Wqb = (u16*)ws;  ws += (size_t)D_DIM * H_DIM * 2;             // 2 MB
  u16* Wkb = (u16*)ws;  ws += (size_t)D_DIM * H_DIM * 2;             // 2 MB
  u16* Wtv = (u16*)ws;  ws += (size_t)H_DIM * D_DIM * 2;             // 2 MB
  u16* Gt = (u16*)ws;   ws += (size_t)D_DIM * D_DIM * 2;             // 2 MB
  u16* Tm = (u16*)ws;   ws += (size_t)M_TOTAL * D_DIM * 2;           // 33.5 MB
  u16* Vt = (u16*)ws;   ws += (size_t)BATCH * H_DIM * S_LEN * 2;     // 33.5 MB
  u16* Sm = (u16*)ws;   ws += (size_t)BATCH * S_LEN * S_LEN * 2;     // 67 MB
  float* bvec = (float*)ws; ws += D_DIM * 4;
  float* vb = (float*)ws;   ws += (size_t)M_TOTAL * 4;               // 64 KB
  float* lsum = (float*)ws; ws += (size_t)M_TOTAL * 4;               // 64 KB

  // 1) prep: x cast, Wq/Wk plain casts, Wv transpose-cast, bvec = Wk*bq, lsum=0
  prep_kernel<<<10496, 256, 0, stream>>>(x, Wq, Wk, Wv, bq, xb, Wqb, Wkb, Wtv,
                                         bvec, lsum);

  // 2) vb[m] = (xb . bvec)/32  — the only bias term that survives softmax
  vvec_kernel<<<M_TOTAL / 4, 256, 0, stream>>>(xb, bvec, vb);

  // 3) Gt = Wk * Wq^T  (M=N=K=1024): B-operand for T = xb*G
  gemm16<0, 0, true><<<dim3(8, 8, 1), 256, 0, stream>>>(
      Wkb, Wqb, Gt, nullptr, nullptr, 1024, 1024, 1024,
      1024, 1024, 1024, 0, 0, 0, 0.f);

  // 4) T = xb * Gt^T  (M=16384, N=1024, K=1024) — replaces the QK projection
  gemm16<0, 0, true><<<dim3(128, 8, 1), 256, 0, stream>>>(
      xb, Gt, Tm, nullptr, nullptr, M_TOTAL, D_DIM, D_DIM,
      1024, 1024, 1024, 0, 0, 0, 0.f);

  // 5) Vt[b][h][s] = Wtv * xb_b^T + bv[row]  (M=1024, N=2048, K=1024, batched)
  gemm16<2, 0, true><<<dim3(8, 16, BATCH), 256, 0, stream>>>(
      Wtv, xb, Vt, bv, nullptr, H_DIM, S_LEN, D_DIM,
      1024, 1024, S_LEN,
      0LL, (long long)S_LEN * D_DIM, (long long)H_DIM * S_LEN, 0.f);

  // 6) P_hat[b][q][k] = exp(T_b xb_b^T / 32 + vb[k]) -> bf16, row sums -> lsum
  gemm16<0, 1, true><<<dim3(16, 16, BATCH), 256, 0, stream>>>(
      Tm, xb, Sm, vb, lsum, S_LEN, S_LEN, D_DIM,
      1024, 1024, S_LEN,
      (long long)S_LEN * D_DIM, (long long)S_LEN * D_DIM,
      (long long)S_LEN * S_LEN, 0.03125f);

  // 7) out[b][q][h] = (P_hat_b / lsum) * Vt_b^T  (M=2048, N=1024, K=2048)
  gemm16<0, 2, false><<<dim3(16, 8, BATCH), 256, 0, stream>>>(
      Sm, Vt, out, nullptr, lsum, S_LEN, H_DIM, S_LEN,
      S_LEN, S_LEN, H_DIM,
      (long long)S_LEN * S_LEN, (long long)H_DIM * S_LEN,
      (long long)S_LEN * H_DIM, 0.f);
}